// Round 6
// baseline (436.008 us; speedup 1.0000x reference)
//
#include <hip/hip_runtime.h>

// BSplineLayer: piecewise-linear spline eval.
// u: [4096,64,256] f32 (channel = fastest axis), knots/coefs: [256,64] f32.
// out[e] = c0 + (x-k0)/(k1-k0+eps) * (c1-c0), segment from searchsorted(left).
//
// v5 (MLP round — ONE variable vs v4; resubmitted after infra failure):
//  - Ladder: v1 434 (64ch/256B) | v2 443 (32 waves+prefetch+nt, confounded)
//    | v3 450 (b128 table -> 8 bank-groups, ~8-way conflict) | v4 435
//    (128ch/512B contiguity, XOR swizzle) ~= v1. Occupancy, LDS shape and
//    DRAM contiguity are all falsified as the residual vs the 6.29 TB/s
//    copy ceiling (kernel ~104us ~= 5.2 TB/s, ceiling would be ~85us).
//  - Untested-clean lever: loads in flight per wave (v2's prefetch was
//    confounded). v4 has a fully serial chain = 1 outstanding load/wave
//    (16KB in flight/CU, marginal vs latency x BW). v5: each thread
//    handles TWO float4s per iteration (rows r and r+16 of a 32-row
//    tile); both global_load_dwordx4 issue before either use -> 2
//    outstanding loads/wave, 32KB in flight/CU, half the loop overhead.
//  - Everything else identical to v4: 128-ch groups, XOR-swizzled LDS
//    (bank = (j ^ (c&31)) % 32, ~2-way), 512-thread blocks, 64KB LDS,
//    2 blocks/CU = 16 waves/CU, grid 512.

#define EPS 1e-6f
#define NCH_GROUP 128
#define NGROUPS 2
#define BLOCKS_PER_GROUP 256
#define ROWS_PER_TILE 32   // 2 float4 rows per thread per iteration

typedef float f32x4 __attribute__((ext_vector_type(4)));

__global__ __launch_bounds__(512) void bspline_kernel(
    const float* __restrict__ u, const float* __restrict__ knots,
    const float* __restrict__ coefs, float* __restrict__ out, int n_rows)
{
    // XOR-swizzled tables: entry (c, j) lives at [c*64 + (j ^ (c&31))].
    // 2 * 128*64*4B = 64KB exactly (static LDS limit).
    __shared__ float sK[NCH_GROUP * 64];
    __shared__ float sC[NCH_GROUP * 64];

    const int t = threadIdx.x;
    const int g = blockIdx.x & (NGROUPS - 1);   // channel group 0..1
    const int b = blockIdx.x >> 1;              // block index within group

    // Stage this group's knots & coefs (8192 floats each, L2/L3-resident
    // after the first blocks) into swizzled LDS.
    const float* gk = knots + (size_t)g * NCH_GROUP * 64;
    const float* gc = coefs + (size_t)g * NCH_GROUP * 64;
    for (int i = t; i < NCH_GROUP * 64; i += 512) {
        int c = i >> 6;
        int j = i & 63;
        int s = (c << 6) | (j ^ (c & 31));
        sK[s] = gk[i];
        sC[s] = gc[i];
    }
    __syncthreads();

    const int col4 = t & 31;        // float4 column within the group
    const int rsub = t >> 5;        // row 0..15 within a tile-half
    const int lc = col4 * 4;        // local channel base (0..124)

    // Per-channel guess parameters (channels fixed per thread).
    float kmin[4], scale[4];
    int xm[4];
#pragma unroll
    for (int cc = 0; cc < 4; ++cc) {
        int c = lc + cc;
        int m = c & 31;
        xm[cc] = m;
        const float* kp = &sK[c << 6];
        float klo = kp[0 ^ m];
        float khi = kp[63 ^ m];
        kmin[cc] = klo;
        scale[cc] = 63.0f * __builtin_amdgcn_rcpf(khi - klo);
    }

    const f32x4* u4 = (const f32x4*)u;
    f32x4* o4 = (f32x4*)out;
    const int colbase = g * 32 + col4;          // float4 column in [0,64)
    const int ntiles = n_rows / ROWS_PER_TILE;

    for (int rt = b; rt < ntiles; rt += BLOCKS_PER_GROUP) {
        int row0 = rt * ROWS_PER_TILE + rsub;   // rows row0 and row0+16
        size_t idx0 = (size_t)row0 * 64 + colbase;
        size_t idx1 = idx0 + (size_t)16 * 64;
        // Issue both loads before either use -> 2 outstanding per wave.
        f32x4 xa = u4[idx0];
        f32x4 xb = u4[idx1];
        f32x4 ra, rb;
#pragma unroll
        for (int h = 0; h < 2; ++h) {
            const f32x4& x4 = h ? xb : xa;
            f32x4& r = h ? rb : ra;
#pragma unroll
            for (int cc = 0; cc < 4; ++cc) {
                float x = x4[cc];
                const int m = xm[cc];
                const float* kp = &sK[(lc + cc) << 6];
                const float* cp = &sC[(lc + cc) << 6];

                // Predictor: analytic segment guess (exact for uniform knots).
                float xs = (x - kmin[cc]) * scale[cc];
                int j = (int)xs;
                j = max(0, min(62, j));
                float k0 = kp[j ^ m];
                float k1 = kp[(j + 1) ^ m];
                // Corrector: exact-compare fixups. Final j satisfies
                // (j==0 || k[j] < x) && (j==62 || k[j+1] >= x)
                //   == clamp(searchsorted_left(k,x)-1, 0, 62), any sorted k.
                while (j > 0 && k0 >= x) { --j; k1 = k0; k0 = kp[j ^ m]; }
                while (j < 62 && k1 < x) { ++j; k0 = k1; k1 = kp[(j + 1) ^ m]; }

                float tt = (x - k0) * __builtin_amdgcn_rcpf(k1 - k0 + EPS);
                float c0 = cp[j ^ m];
                float c1 = cp[(j + 1) ^ m];
                r[cc] = fmaf(tt, c1 - c0, c0);
            }
        }
        o4[idx0] = ra;
        o4[idx1] = rb;
    }
}

extern "C" void kernel_launch(void* const* d_in, const int* in_sizes, int n_in,
                              void* d_out, int out_size, void* d_ws, size_t ws_size,
                              hipStream_t stream) {
    const float* u     = (const float*)d_in[0];
    const float* knots = (const float*)d_in[1];
    const float* coefs = (const float*)d_in[2];
    float* out = (float*)d_out;

    int n_rows = in_sizes[0] / 256;   // 262144 rows of 256 channels

    dim3 grid(NGROUPS * BLOCKS_PER_GROUP);   // 512 blocks = 2/CU, 16 waves/CU
    dim3 block(512);
    bspline_kernel<<<grid, block, 0, stream>>>(u, knots, coefs, out, n_rows);
}